// Round 15
// baseline (136.365 us; speedup 1.0000x reference)
//
#include <hip/hip_runtime.h>

typedef short bf16x8 __attribute__((ext_vector_type(8)));
typedef float f32x4 __attribute__((ext_vector_type(4)));
typedef float f32x16 __attribute__((ext_vector_type(16)));

#define MFMA16(a, b, c) __builtin_amdgcn_mfma_f32_16x16x32_bf16((a), (b), (c), 0, 0, 0)
#define MFMA32(a, b, c) __builtin_amdgcn_mfma_f32_32x32x16_bf16((a), (b), (c), 0, 0, 0)

#define GLOAD_LDS16(g, l)                                              \
  __builtin_amdgcn_global_load_lds(                                    \
      (const __attribute__((address_space(1))) unsigned int*)(g),      \
      (__attribute__((address_space(3))) unsigned int*)(l), 16, 0, 0)

__device__ __forceinline__ unsigned short f2b(float f) {
  union { float f; unsigned int u; } x; x.f = f;
  unsigned int r = x.u + 0x7FFFu + ((x.u >> 16) & 1u);
  return (unsigned short)(r >> 16);
}
__device__ __forceinline__ float b2f(unsigned short h) {
  union { unsigned int u; float f; } x; x.u = ((unsigned int)h) << 16;
  return x.f;
}
__device__ __forceinline__ unsigned int cvtpk(float lo, float hi) {
  unsigned int r;
  asm("v_cvt_pk_bf16_f32 %0, %1, %2" : "=v"(r) : "v"(lo), "v"(hi));
  return r;
}
__device__ __forceinline__ short cvt1(float x) {
  return (short)(unsigned short)cvtpk(x, x);
}
__device__ __forceinline__ float vexp2(float x) {  // raw v_exp_f32 (base-2)
  float r;
  asm("v_exp_f32 %0, %1" : "=v"(r) : "v"(x));
  return r;
}

#define SCALE2 0.06375870724f  // log2(e)/sqrt(512)

// ---------------- merged prep: blocks [0,256) = weight transpose (Wk pre-scaled),
//                  blocks [256,4352) = Q/K f32->bf16 convert + bf16 mask build
__global__ __launch_bounds__(256) void prep_kernel(
    const float* __restrict__ Wq, const float* __restrict__ Wk,
    const float* __restrict__ Wv, const float* __restrict__ Wo,
    const float* __restrict__ Q, const float* __restrict__ K,
    const float* __restrict__ mask,
    short* __restrict__ Wt, short* __restrict__ Qb, short* __restrict__ Kb,
    short* __restrict__ mbf) {
  __shared__ float tile[64][65];
  const int bid = blockIdx.x;
  const int t = threadIdx.x;
  if (bid < 256) {
    const int z = bid >> 6;
    const int rem = bid & 63;
    const int k0 = (rem >> 3) * 64, n0 = (rem & 7) * 64;
    const float* W = (z == 0) ? Wq : (z == 1) ? Wk : (z == 2) ? Wv : Wo;
    const float ws = (z == 1) ? SCALE2 : 1.0f;
    const int r = t >> 4, cc = (t & 15) * 4;
#pragma unroll
    for (int it = 0; it < 4; ++it) {
      int row = r + it * 16;
      const float4 v = *(const float4*)(W + (k0 + row) * 512 + n0 + cc);
      tile[row][cc + 0] = v.x; tile[row][cc + 1] = v.y;
      tile[row][cc + 2] = v.z; tile[row][cc + 3] = v.w;
    }
    __syncthreads();
    short* out = Wt + z * (512 * 512);
#pragma unroll
    for (int it = 0; it < 4; ++it) {
      int nrow = r + it * 16;
      unsigned int u0 = cvtpk(tile[cc + 0][nrow] * ws, tile[cc + 1][nrow] * ws);
      unsigned int u1 = cvtpk(tile[cc + 2][nrow] * ws, tile[cc + 3][nrow] * ws);
      uint2 uv; uv.x = u0; uv.y = u1;
      *(uint2*)(out + (n0 + nrow) * 512 + k0 + cc) = uv;
    }
  } else {
    const int idx = bid - 256;
    const int ybit = idx >> 11;
    const int x = idx & 2047;
    if (ybit == 0 && x < 4) {
      int i = (x * 256 + t) * 8;
      float4 a = *(const float4*)(mask + i);
      float4 bb = *(const float4*)(mask + i + 4);
      unsigned int m0 = (a.x != 0.f) ? 0x3F80u : 0u;
      unsigned int m1 = (a.y != 0.f) ? 0x3F80u : 0u;
      unsigned int m2 = (a.z != 0.f) ? 0x3F80u : 0u;
      unsigned int m3 = (a.w != 0.f) ? 0x3F80u : 0u;
      unsigned int m4 = (bb.x != 0.f) ? 0x3F80u : 0u;
      unsigned int m5 = (bb.y != 0.f) ? 0x3F80u : 0u;
      unsigned int m6 = (bb.z != 0.f) ? 0x3F80u : 0u;
      unsigned int m7 = (bb.w != 0.f) ? 0x3F80u : 0u;
      uint4 mm;
      mm.x = m0 | (m1 << 16); mm.y = m2 | (m3 << 16);
      mm.z = m4 | (m5 << 16); mm.w = m6 | (m7 << 16);
      *(uint4*)(mbf + i) = mm;
    }
    const float* src = ybit ? K : Q;
    short* dst = ybit ? Kb : Qb;
    int i = (x * 256 + t) * 8;
    float4 v0 = *(const float4*)(src + i);
    float4 v1 = *(const float4*)(src + i + 4);
    uint2 a, b;
    a.x = cvtpk(v0.x, v0.y); a.y = cvtpk(v0.z, v0.w);
    b.x = cvtpk(v1.x, v1.y); b.y = cvtpk(v1.z, v1.w);
    *(uint2*)(dst + i) = a;
    *(uint2*)(dst + i + 4) = b;
  }
}

// ---------------- GEMM mainloop: 128x128 tile, BK=64, single-buffer LDS (32KB) + T2 swizzle
__device__ __forceinline__ void gemm_bf16_core(
    const short* __restrict__ A, const short* __restrict__ Wt,
    short* Lb, int m0, int t, f32x4 acc[4][4]) {
  const int lane = t & 63, w = t >> 6;
  const int c = lane & 15, g = lane >> 4;
  const int wr = w >> 1, wc = w & 1;
  const int lr = lane >> 3;
  const int sswz = ((lane & 7) ^ lr) << 3;
  const int swc = (c & 7) << 3;
  short* Al = Lb;
  short* Bl = Lb + 8192;

  for (int kt = 0; kt < 8; ++kt) {
#pragma unroll
    for (int it = 0; it < 4; ++it) {
      int row = w * 32 + it * 8;
      GLOAD_LDS16(A + (size_t)(m0 + row + lr) * 512 + kt * 64 + sswz, Al + row * 64);
      GLOAD_LDS16(Wt + (size_t)(row + lr) * 512 + kt * 64 + sswz, Bl + row * 64);
    }
    __syncthreads();
    __builtin_amdgcn_s_setprio(1);
#pragma unroll
    for (int kc = 0; kc < 2; ++kc) {
      bf16x8 af[4], bfr[4];
#pragma unroll
      for (int mi = 0; mi < 4; ++mi) {
        int r = wr * 64 + mi * 16 + c;
        af[mi] = *(const bf16x8*)(Al + r * 64 + ((kc * 32 + 8 * g) ^ swc));
      }
#pragma unroll
      for (int ni = 0; ni < 4; ++ni) {
        int r = wc * 64 + ni * 16 + c;
        bfr[ni] = *(const bf16x8*)(Bl + r * 64 + ((kc * 32 + 8 * g) ^ swc));
      }
#pragma unroll
      for (int mi = 0; mi < 4; ++mi)
#pragma unroll
        for (int ni = 0; ni < 4; ++ni)
          acc[mi][ni] = MFMA16(af[mi], bfr[ni], acc[mi][ni]);
    }
    __builtin_amdgcn_s_setprio(0);
    __syncthreads();
  }
}

// ---------------- fused projections (LDS-transpose epilogue, coalesced stores)
__global__ __launch_bounds__(256) void proj2_kernel(
    const short* __restrict__ Qb, const short* __restrict__ Kb,
    const short* __restrict__ Wt4,
    const float* __restrict__ bq, const float* __restrict__ bk, const float* __restrict__ bv,
    const float* __restrict__ maskf,
    short* __restrict__ Qp, short* __restrict__ Kp, short* __restrict__ Vt) {
  __shared__ short Lbuf[16384];
  const int by = blockIdx.y;
  const int m0 = blockIdx.x * 128;
  const int t = threadIdx.x;
  const short* A;
  const short* Wt;
  const float* bias;
  int nbase;
  if (by < 4) { A = Qb; nbase = by * 128; Wt = Wt4 + nbase * 512; bias = bq; }
  else if (by < 8) { A = Kb; nbase = (by - 4) * 128; Wt = Wt4 + 262144 + nbase * 512; bias = bk; }
  else { A = Kb; nbase = (by - 8) * 128; Wt = Wt4 + 524288 + nbase * 512; bias = bv; }
  const float bscale = (by >= 4 && by < 8) ? SCALE2 : 1.0f;

  const f32x4 zz = {0.f, 0.f, 0.f, 0.f};
  f32x4 acc[4][4];
#pragma unroll
  for (int mi = 0; mi < 4; ++mi)
#pragma unroll
    for (int ni = 0; ni < 4; ++ni) acc[mi][ni] = zz;
  gemm_bf16_core(A, Wt, Lbuf, m0, t, acc);

  const int lane = t & 63, w = t >> 6;
  const int c = lane & 15, g = lane >> 4;
  const int wr = w >> 1, wc = w & 1;
  float mk[4][4];
#pragma unroll
  for (int mi = 0; mi < 4; ++mi) {
    int mbase = m0 + wr * 64 + mi * 16 + 4 * g;
#pragma unroll
    for (int i = 0; i < 4; ++i) mk[mi][i] = maskf[mbase + i];
  }
  float bval[4];
#pragma unroll
  for (int ni = 0; ni < 4; ++ni) bval[ni] = bias[nbase + wc * 64 + ni * 16 + c] * bscale;

  if (by < 8) {
#pragma unroll
    for (int ni = 0; ni < 4; ++ni) {
      int nloc = wc * 64 + ni * 16 + c;
#pragma unroll
      for (int mi = 0; mi < 4; ++mi) {
#pragma unroll
        for (int i = 0; i < 4; ++i) {
          int mloc = wr * 64 + mi * 16 + 4 * g + i;
          float v = (acc[mi][ni][i] + bval[ni]) * mk[mi][i];
          Lbuf[mloc * 128 + (nloc ^ ((mloc & 7) << 3))] = cvt1(v);
        }
      }
    }
    __syncthreads();
    short* outp = (by < 4) ? Qp : Kp;
    const int rrow = t >> 4, rcol = (t & 15) * 8;
#pragma unroll
    for (int p = 0; p < 8; ++p) {
      int m = p * 16 + rrow;
      bf16x8 vv = *(const bf16x8*)(Lbuf + m * 128 + (rcol ^ ((m & 7) << 3)));
      *(bf16x8*)(outp + (size_t)(m0 + m) * 512 + nbase + rcol) = vv;
    }
  } else {
#pragma unroll
    for (int ni = 0; ni < 4; ++ni) {
      int nloc = wc * 64 + ni * 16 + c;
#pragma unroll
      for (int mi = 0; mi < 4; ++mi) {
        int mloc4 = wr * 64 + mi * 16 + 4 * g;
        unsigned int lo = cvtpk((acc[mi][ni][0] + bval[ni]) * mk[mi][0],
                                (acc[mi][ni][1] + bval[ni]) * mk[mi][1]);
        unsigned int hi = cvtpk((acc[mi][ni][2] + bval[ni]) * mk[mi][2],
                                (acc[mi][ni][3] + bval[ni]) * mk[mi][3]);
        int ma = (mloc4 & 15) + (((mloc4 >> 4) ^ (nloc & 7)) << 4);
        uint2 uv; uv.x = lo; uv.y = hi;
        *(uint2*)(Lbuf + nloc * 128 + ma) = uv;
      }
    }
    __syncthreads();
    const int rrow = t >> 4, rcol = (t & 15) * 8;
#pragma unroll
    for (int p = 0; p < 8; ++p) {
      int n = p * 16 + rrow;
      int ma = (rcol & 8) + (((rcol >> 4) ^ (n & 7)) << 4);
      bf16x8 vv = *(const bf16x8*)(Lbuf + n * 128 + ma);
      int d = nbase + n;
      int hh = d >> 6, dd = d & 63;
      int mg = m0 + rcol;
      int bi = mg >> 10, seq0 = mg & 1023;
      *(bf16x8*)(Vt + ((size_t)((bi * 8 + hh) * 64 + dd)) * 1024 + seq0) = vv;
    }
  }
}

// ---------------- flash attention v10: attn7 schedule, SINGLE-buffered (18 KB LDS),
// __launch_bounds__(128,4) -> 8 blocks/CU = 16 waves/CU. 2 waves x 32 q-rows,
// KVBLK=64 in two kv-32 halves, 32x32 MFMA, in-register P, masked denominator,
// packed [r2][128] 16-slot-XOR layouts (2-way free).
__global__ __launch_bounds__(128, 4) void attn10_kernel(
    const short* __restrict__ Qp, const short* __restrict__ Kp,
    const short* __restrict__ Vt, const float* __restrict__ mask,
    const short* __restrict__ mbf, short* __restrict__ Obb) {
  __shared__ short Kl[32 * 128];  // 8 KB; reused as wave0's epilogue Tw
  __shared__ short Vl[32 * 128];  // 8 KB; reused as wave1's epilogue Tw
  __shared__ short Ml[1024];      // 2 KB bf16 mask row
  const int t = threadIdx.x, lane = t & 63, w = t >> 6;  // w in {0,1}
  const int q32 = lane & 31, hi = lane >> 5;
  const int hw = blockIdx.x;
  const int L = (hw & 7) * 128 + (hw >> 3);  // XCD swizzle: 8 heads/XCD
  const int qt = L & 15, head = L >> 4;
  const int b = head & 7, h = head >> 3;
  const int n0 = qt * 64 + w * 32;

  const short* Kg = Kp + (size_t)(b * 1024) * 512 + h * 64;
  const short* Vg = Vt + (size_t)((b * 8 + h) * 64) * 1024;

  bf16x8 qf[4];
  {
    const short* qptr = Qp + ((size_t)(b * 1024 + n0 + q32) * 512 + h * 64 + 8 * hi);
#pragma unroll
    for (int kk = 0; kk < 4; ++kk) qf[kk] = *(const bf16x8*)(qptr + 16 * kk);
  }
  asm volatile("s_waitcnt vmcnt(0)" ::: "memory");  // qf resolved; clean vm counting
  __builtin_amdgcn_sched_barrier(0);

  // staging split across the 2 waves: 4 K + 4 V gload_lds per wave per tile
  auto STAGE = [&](int kvt) {
    const int kr = kvt * 64;
#pragma unroll
    for (int it = 0; it < 4; ++it) {
      int rb = it * 8 + w * 4;
      int r2 = rb + (lane >> 4);
      int sx = (lane & 15) ^ (r2 & 15);
      GLOAD_LDS16(Kg + (size_t)(kr + 2 * r2 + (sx >> 3)) * 512 + (sx & 7) * 8, Kl + rb * 128);
    }
#pragma unroll
    for (int it = 0; it < 4; ++it) {
      int rb = it * 8 + w * 4;
      int rv = rb + (lane >> 4);
      int sx = (lane & 15) ^ (rv & 15);
      GLOAD_LDS16(Vg + (size_t)(2 * rv + (sx >> 3)) * 1024 + kr + (sx & 7) * 8, Vl + rb * 128);
    }
  };

  // prologue: mask row + tile 0
  GLOAD_LDS16(mbf + b * 1024 + w * 512 + lane * 8, Ml + w * 512);
  STAGE(0);

  f32x16 o0, o1, suma;
#pragma unroll
  for (int e = 0; e < 16; ++e) { o0[e] = 0.f; o1[e] = 0.f; suma[e] = 0.f; }

#pragma unroll 1
  for (int kvt = 0; kvt < 16; ++kvt) {
    asm volatile("s_waitcnt vmcnt(0)" ::: "memory");
    __builtin_amdgcn_sched_barrier(0);
    __builtin_amdgcn_s_barrier();  // staged tile visible to both waves
    __builtin_amdgcn_sched_barrier(0);

#pragma unroll
    for (int half = 0; half < 2; ++half) {
      // ---- just-in-time fragment reads for this kv-32 half
      bf16x8 ka[4], va[2][2], mo[2];
      {
        const int kvr = 32 * half + q32;
        const int r2 = kvr >> 1;
#pragma unroll
        for (int kk = 0; kk < 4; ++kk) {
          int sx = ((((kvr & 1) << 3) | (2 * kk + hi)) ^ (r2 & 15));
          ka[kk] = *(const bf16x8*)(Kl + r2 * 128 + sx * 8);
        }
      }
#pragma unroll
      for (int ds = 0; ds < 2; ++ds) {
        const int d = 32 * ds + q32;
        const int rv = d >> 1;
#pragma unroll
        for (int ch = 0; ch < 2; ++ch) {
          int sx = ((((d & 1) << 3) | (4 * half + 2 * ch + hi)) ^ (rv & 15));
          va[ds][ch] = *(const bf16x8*)(Vl + rv * 128 + sx * 8);
        }
      }
#pragma unroll
      for (int ch = 0; ch < 2; ++ch)  // broadcast
        mo[ch] = *(const bf16x8*)(Ml + kvt * 64 + 32 * half + 16 * ch + 8 * hi);

      __builtin_amdgcn_sched_barrier(0);
      asm volatile("s_waitcnt lgkmcnt(0)" ::: "memory");
      __builtin_amdgcn_sched_barrier(0);
      if (half == 1) {
        __builtin_amdgcn_s_barrier();  // all reads of this tile done (both waves)
        __builtin_amdgcn_sched_barrier(0);
        if (kvt < 15) STAGE(kvt + 1);  // overlaps half-1 compute
        __builtin_amdgcn_sched_barrier(0);
      }

      // ---- QK^T for this half
      f32x16 s0;
#pragma unroll
      for (int e = 0; e < 16; ++e) s0[e] = 0.f;
      __builtin_amdgcn_s_setprio(1);
#pragma unroll
      for (int kk = 0; kk < 4; ++kk) s0 = MFMA32(ka[kk], qf[kk], s0);
      __builtin_amdgcn_s_setprio(0);

      // ---- p = exp2(s) (scale pre-folded into Kp)
      f32x16 p0;
#pragma unroll
      for (int e = 0; e < 16; ++e) p0[e] = vexp2(s0[e]);

      // ---- pack P^T fragments via cvt_pk + shfl_xor(32)
      bf16x8 pf[2];
#pragma unroll
      for (int ch = 0; ch < 2; ++ch) {
        unsigned int w01a = cvtpk(p0[8 * ch + 0], p0[8 * ch + 1]);
        unsigned int w01b = cvtpk(p0[8 * ch + 2], p0[8 * ch + 3]);
        unsigned int w23a = cvtpk(p0[8 * ch + 4], p0[8 * ch + 5]);
        unsigned int w23b = cvtpk(p0[8 * ch + 6], p0[8 * ch + 7]);
        unsigned int x0 = hi ? w01a : w23a;
        unsigned int x1 = hi ? w01b : w23b;
        unsigned int g0 = (unsigned int)__shfl_xor((int)x0, 32);
        unsigned int g1 = (unsigned int)__shfl_xor((int)x1, 32);
        union { unsigned int u[4]; bf16x8 v; } pu;
        pu.u[0] = hi ? g0 : w01a;
        pu.u[1] = hi ? g1 : w01b;
        pu.u[2] = hi ? w23a : g0;
        pu.u[3] = hi ? w23b : g1;
        pf[ch] = pu.v;
      }

      // ---- PV + masked denominator
      __builtin_amdgcn_s_setprio(1);
#pragma unroll
      for (int ch = 0; ch < 2; ++ch) {
        o0 = MFMA32(va[0][ch], pf[ch], o0);
        o1 = MFMA32(va[1][ch], pf[ch], o1);
        suma = MFMA32(mo[ch], pf[ch], suma);
      }
      __builtin_amdgcn_s_setprio(0);
    }
  }

  // ---- epilogue: wave-private Tw (w0 -> Kl, w1 -> Vl), residual + row-mask
  __builtin_amdgcn_s_barrier();  // both waves done with K/V buffers
  __builtin_amdgcn_sched_barrier(0);
  short* Tw = (w == 0) ? Kl : Vl;  // 32x68 padded fits in 4096 shorts
  const float inv = __builtin_amdgcn_rcpf(suma[0] + 1e-16f);
#pragma unroll
  for (int rr = 0; rr < 4; ++rr) {
    uint2 uv0, uv1;
    uv0.x = cvtpk(o0[4 * rr + 0] * inv, o0[4 * rr + 1] * inv);
    uv0.y = cvtpk(o0[4 * rr + 2] * inv, o0[4 * rr + 3] * inv);
    *(uint2*)(Tw + q32 * 68 + 8 * rr + 4 * hi) = uv0;
    uv1.x = cvtpk(o1[4 * rr + 0] * inv, o1[4 * rr + 1] * inv);
    uv1.y = cvtpk(o1[4 * rr + 2] * inv, o1[4 * rr + 3] * inv);
    *(uint2*)(Tw + q32 * 68 + 32 + 8 * rr + 4 * hi) = uv1;
  }
  asm volatile("s_waitcnt lgkmcnt(0)" ::: "memory");
  __builtin_amdgcn_sched_barrier(0);

  const int erow = lane >> 1, ecs = (lane & 1) * 8;
  const float mk1 = mask[b * 1024 + n0 + erow];
#pragma unroll
  for (int it = 0; it < 4; ++it) {
    int col = ecs + it * 16;
    bf16x8 av = *(const bf16x8*)(Tw + erow * 68 + col);
    const short* qptr = Qp + (size_t)(b * 1024 + n0 + erow) * 512 + h * 64 + col;
    bf16x8 qv = *(const bf16x8*)qptr;
    uint4 rr;
    rr.x = cvtpk(b2f((unsigned short)qv[0]) + mk1 * b2f((unsigned short)av[0]),
                 b2f((unsigned short)qv[1]) + mk1 * b2f((unsigned short)av[1]));
    rr.y = cvtpk(b2f((unsigned short)qv[2]) + mk1 * b2f((unsigned short)av[2]),
                 b2f((unsigned short)qv[3]) + mk1 * b2f((unsigned short)av[3]));
    rr.z = cvtpk(b2f((unsigned short)qv[4]) + mk1 * b2f((unsigned short)av[4]),
                 b2f((unsigned short)qv[5]) + mk1 * b2f((unsigned short)av[5]));
    rr.w = cvtpk(b2f((unsigned short)qv[6]) + mk1 * b2f((unsigned short)av[6]),
                 b2f((unsigned short)qv[7]) + mk1 * b2f((unsigned short)av[7]));
    *(uint4*)(Obb + (size_t)(b * 1024 + n0 + erow) * 512 + h * 64 + col) = rr;
  }
}

// ---------------- final: out = Obb + relu((Obb@Wo + bo) * mask)
__global__ __launch_bounds__(256) void final2_kernel(
    const short* __restrict__ Obb,
    const short* __restrict__ Wto, const float* __restrict__ bo,
    const float* __restrict__ maskf, float* __restrict__ out) {
  __shared__ short Lbuf[16384];
  const int m0 = blockIdx.x * 128, n0 = blockIdx.y * 128;
  const int t = threadIdx.x;
  const f32x4 zz = {0.f, 0.f, 0.f, 0.f};
  f32x4 acc[4][4];
#pragma unroll
  for (int mi = 0; mi < 4; ++mi)
#pragma unroll
    for (int ni = 0; ni < 4; ++ni) acc[mi][ni] = zz;
  gemm_bf16_core(Obb, Wto + n0 * 512, Lbuf, m0, t, acc);

  const int lane = t & 63, w = t >> 6;
  const int c = lane & 15, g = lane >> 4;
  const int wr = w >> 1, wc = w & 1;
  float mk[4][4];
#pragma unroll
  for (int mi = 0; mi < 4; ++mi) {
    int mbase = m0 + wr * 64 + mi * 16 + 4 * g;
#pragma unroll
    for (int i = 0; i < 4; ++i) mk[mi][i] = maskf[mbase + i];
  }
#pragma unroll
  for (int ni = 0; ni < 4; ++ni) {
    int n = n0 + wc * 64 + ni * 16 + c;
    float bval = bo[n];
#pragma unroll
    for (int mi = 0; mi < 4; ++mi) {
      int mbase = m0 + wr * 64 + mi * 16 + 4 * g;
#pragma unroll
      for (int i = 0; i < 4; ++i) {
        float v = (acc[mi][ni][i] + bval) * mk[mi][i];
        v = fmaxf(v, 0.f);
        size_t off = (size_t)(mbase + i) * 512 + n;
        out[off] = b2f((unsigned short)Obb[off]) + v;
      }
    }
  }
}

extern "C" void kernel_launch(void* const* d_in, const int* in_sizes, int n_in,
                              void* d_out, int out_size, void* d_ws, size_t ws_size,
                              hipStream_t stream) {
  (void)in_sizes; (void)n_in; (void)out_size; (void)ws_size;
  const float* Q    = (const float*)d_in[0];
  const float* K    = (const float*)d_in[1];
  const float* mask = (const float*)d_in[2];
  const float* Wq   = (const float*)d_in[3];
  const float* bq   = (const float*)d_in[4];
  const float* Wk   = (const float*)d_in[5];
  const float* bk   = (const float*)d_in[6];
  const float* Wv   = (const float*)d_in[7];
  const float* bv   = (const float*)d_in[8];
  const float* Wo   = (const float*)d_in[9];
  const float* bo   = (const float*)d_in[10];

  char* ws = (char*)d_ws;
  const size_t MB = 1048576;
  short* Wt4 = (short*)ws;                 // 0-2 MB (Wk pre-scaled by SCALE2)
  short* Qb  = (short*)(ws + 2 * MB);      // 2-10 MB (dead after proj2)
  short* Kb  = (short*)(ws + 10 * MB);     // 10-18 MB (dead after proj2)
  short* Qp  = (short*)(ws + 18 * MB);     // 18-26 MB
  short* Kp  = (short*)(ws + 26 * MB);     // 26-34 MB (pre-scaled)
  short* Vt  = (short*)(ws + 34 * MB);     // 34-42 MB: [B][H][64][1024]
  short* Obb = (short*)(ws + 42 * MB);     // 42-50 MB
  short* mbf = (short*)(ws + 50 * MB);     // 16 KB bf16 mask
  float* out = (float*)d_out;

  prep_kernel<<<dim3(4352), 256, 0, stream>>>(Wq, Wk, Wv, Wo, Q, K, mask, Wt4, Qb, Kb, mbf);
  proj2_kernel<<<dim3(64, 12), 256, 0, stream>>>(Qb, Kb, Wt4, bq, bk, bv, mask, Qp, Kp, Vt);
  attn10_kernel<<<dim3(1024), 128, 0, stream>>>(Qp, Kp, Vt, mask, mbf, Obb);
  final2_kernel<<<dim3(64, 4), 256, 0, stream>>>(Obb, Wt4 + 3 * 262144, bo, mask, out);
}

// Round 16
// 79.733 us; speedup vs baseline: 1.7103x; 1.7103x over previous
//
#include <hip/hip_runtime.h>

typedef short bf16x8 __attribute__((ext_vector_type(8)));
typedef float f32x4 __attribute__((ext_vector_type(4)));
typedef float f32x16 __attribute__((ext_vector_type(16)));

#define MFMA16(a, b, c) __builtin_amdgcn_mfma_f32_16x16x32_bf16((a), (b), (c), 0, 0, 0)
#define MFMA32(a, b, c) __builtin_amdgcn_mfma_f32_32x32x16_bf16((a), (b), (c), 0, 0, 0)

#define GLOAD_LDS16(g, l)                                              \
  __builtin_amdgcn_global_load_lds(                                    \
      (const __attribute__((address_space(1))) unsigned int*)(g),      \
      (__attribute__((address_space(3))) unsigned int*)(l), 16, 0, 0)

__device__ __forceinline__ unsigned short f2b(float f) {
  union { float f; unsigned int u; } x; x.f = f;
  unsigned int r = x.u + 0x7FFFu + ((x.u >> 16) & 1u);
  return (unsigned short)(r >> 16);
}
__device__ __forceinline__ float b2f(unsigned short h) {
  union { unsigned int u; float f; } x; x.u = ((unsigned int)h) << 16;
  return x.f;
}
__device__ __forceinline__ unsigned int cvtpk(float lo, float hi) {
  unsigned int r;
  asm("v_cvt_pk_bf16_f32 %0, %1, %2" : "=v"(r) : "v"(lo), "v"(hi));
  return r;
}
__device__ __forceinline__ short cvt1(float x) {
  return (short)(unsigned short)cvtpk(x, x);
}
__device__ __forceinline__ float vexp2(float x) {  // raw v_exp_f32 (base-2)
  float r;
  asm("v_exp_f32 %0, %1" : "=v"(r) : "v"(x));
  return r;
}

#define SCALE2 0.06375870724f  // log2(e)/sqrt(512)

// ---------------- merged prep: blocks [0,256) = weight transpose (Wk pre-scaled),
//                  blocks [256,4352) = Q/K f32->bf16 convert + bf16 mask build
__global__ __launch_bounds__(256) void prep_kernel(
    const float* __restrict__ Wq, const float* __restrict__ Wk,
    const float* __restrict__ Wv, const float* __restrict__ Wo,
    const float* __restrict__ Q, const float* __restrict__ K,
    const float* __restrict__ mask,
    short* __restrict__ Wt, short* __restrict__ Qb, short* __restrict__ Kb,
    short* __restrict__ mbf) {
  __shared__ float tile[64][65];
  const int bid = blockIdx.x;
  const int t = threadIdx.x;
  if (bid < 256) {
    const int z = bid >> 6;
    const int rem = bid & 63;
    const int k0 = (rem >> 3) * 64, n0 = (rem & 7) * 64;
    const float* W = (z == 0) ? Wq : (z == 1) ? Wk : (z == 2) ? Wv : Wo;
    const float ws = (z == 1) ? SCALE2 : 1.0f;
    const int r = t >> 4, cc = (t & 15) * 4;
#pragma unroll
    for (int it = 0; it < 4; ++it) {
      int row = r + it * 16;
      const float4 v = *(const float4*)(W + (k0 + row) * 512 + n0 + cc);
      tile[row][cc + 0] = v.x; tile[row][cc + 1] = v.y;
      tile[row][cc + 2] = v.z; tile[row][cc + 3] = v.w;
    }
    __syncthreads();
    short* out = Wt + z * (512 * 512);
#pragma unroll
    for (int it = 0; it < 4; ++it) {
      int nrow = r + it * 16;
      unsigned int u0 = cvtpk(tile[cc + 0][nrow] * ws, tile[cc + 1][nrow] * ws);
      unsigned int u1 = cvtpk(tile[cc + 2][nrow] * ws, tile[cc + 3][nrow] * ws);
      uint2 uv; uv.x = u0; uv.y = u1;
      *(uint2*)(out + (n0 + nrow) * 512 + k0 + cc) = uv;
    }
  } else {
    const int idx = bid - 256;
    const int ybit = idx >> 11;
    const int x = idx & 2047;
    if (ybit == 0 && x < 4) {
      int i = (x * 256 + t) * 8;
      float4 a = *(const float4*)(mask + i);
      float4 bb = *(const float4*)(mask + i + 4);
      unsigned int m0 = (a.x != 0.f) ? 0x3F80u : 0u;
      unsigned int m1 = (a.y != 0.f) ? 0x3F80u : 0u;
      unsigned int m2 = (a.z != 0.f) ? 0x3F80u : 0u;
      unsigned int m3 = (a.w != 0.f) ? 0x3F80u : 0u;
      unsigned int m4 = (bb.x != 0.f) ? 0x3F80u : 0u;
      unsigned int m5 = (bb.y != 0.f) ? 0x3F80u : 0u;
      unsigned int m6 = (bb.z != 0.f) ? 0x3F80u : 0u;
      unsigned int m7 = (bb.w != 0.f) ? 0x3F80u : 0u;
      uint4 mm;
      mm.x = m0 | (m1 << 16); mm.y = m2 | (m3 << 16);
      mm.z = m4 | (m5 << 16); mm.w = m6 | (m7 << 16);
      *(uint4*)(mbf + i) = mm;
    }
    const float* src = ybit ? K : Q;
    short* dst = ybit ? Kb : Qb;
    int i = (x * 256 + t) * 8;
    float4 v0 = *(const float4*)(src + i);
    float4 v1 = *(const float4*)(src + i + 4);
    uint2 a, b;
    a.x = cvtpk(v0.x, v0.y); a.y = cvtpk(v0.z, v0.w);
    b.x = cvtpk(v1.x, v1.y); b.y = cvtpk(v1.z, v1.w);
    *(uint2*)(dst + i) = a;
    *(uint2*)(dst + i + 4) = b;
  }
}

// ---------------- GEMM mainloop: 128x128 tile, BK=64, single-buffer LDS (32KB) + T2 swizzle
__device__ __forceinline__ void gemm_bf16_core(
    const short* __restrict__ A, const short* __restrict__ Wt,
    short* Lb, int m0, int t, f32x4 acc[4][4]) {
  const int lane = t & 63, w = t >> 6;
  const int c = lane & 15, g = lane >> 4;
  const int wr = w >> 1, wc = w & 1;
  const int lr = lane >> 3;
  const int sswz = ((lane & 7) ^ lr) << 3;
  const int swc = (c & 7) << 3;
  short* Al = Lb;
  short* Bl = Lb + 8192;

  for (int kt = 0; kt < 8; ++kt) {
#pragma unroll
    for (int it = 0; it < 4; ++it) {
      int row = w * 32 + it * 8;
      GLOAD_LDS16(A + (size_t)(m0 + row + lr) * 512 + kt * 64 + sswz, Al + row * 64);
      GLOAD_LDS16(Wt + (size_t)(row + lr) * 512 + kt * 64 + sswz, Bl + row * 64);
    }
    __syncthreads();
    __builtin_amdgcn_s_setprio(1);
#pragma unroll
    for (int kc = 0; kc < 2; ++kc) {
      bf16x8 af[4], bfr[4];
#pragma unroll
      for (int mi = 0; mi < 4; ++mi) {
        int r = wr * 64 + mi * 16 + c;
        af[mi] = *(const bf16x8*)(Al + r * 64 + ((kc * 32 + 8 * g) ^ swc));
      }
#pragma unroll
      for (int ni = 0; ni < 4; ++ni) {
        int r = wc * 64 + ni * 16 + c;
        bfr[ni] = *(const bf16x8*)(Bl + r * 64 + ((kc * 32 + 8 * g) ^ swc));
      }
#pragma unroll
      for (int mi = 0; mi < 4; ++mi)
#pragma unroll
        for (int ni = 0; ni < 4; ++ni)
          acc[mi][ni] = MFMA16(af[mi], bfr[ni], acc[mi][ni]);
    }
    __builtin_amdgcn_s_setprio(0);
    __syncthreads();
  }
}

// ---------------- fused projections (LDS-transpose epilogue, coalesced stores)
__global__ __launch_bounds__(256) void proj2_kernel(
    const short* __restrict__ Qb, const short* __restrict__ Kb,
    const short* __restrict__ Wt4,
    const float* __restrict__ bq, const float* __restrict__ bk, const float* __restrict__ bv,
    const float* __restrict__ maskf,
    short* __restrict__ Qp, short* __restrict__ Kp, short* __restrict__ Vt) {
  __shared__ short Lbuf[16384];
  const int by = blockIdx.y;
  const int m0 = blockIdx.x * 128;
  const int t = threadIdx.x;
  const short* A;
  const short* Wt;
  const float* bias;
  int nbase;
  if (by < 4) { A = Qb; nbase = by * 128; Wt = Wt4 + nbase * 512; bias = bq; }
  else if (by < 8) { A = Kb; nbase = (by - 4) * 128; Wt = Wt4 + 262144 + nbase * 512; bias = bk; }
  else { A = Kb; nbase = (by - 8) * 128; Wt = Wt4 + 524288 + nbase * 512; bias = bv; }
  const float bscale = (by >= 4 && by < 8) ? SCALE2 : 1.0f;

  const f32x4 zz = {0.f, 0.f, 0.f, 0.f};
  f32x4 acc[4][4];
#pragma unroll
  for (int mi = 0; mi < 4; ++mi)
#pragma unroll
    for (int ni = 0; ni < 4; ++ni) acc[mi][ni] = zz;
  gemm_bf16_core(A, Wt, Lbuf, m0, t, acc);

  const int lane = t & 63, w = t >> 6;
  const int c = lane & 15, g = lane >> 4;
  const int wr = w >> 1, wc = w & 1;
  float mk[4][4];
#pragma unroll
  for (int mi = 0; mi < 4; ++mi) {
    int mbase = m0 + wr * 64 + mi * 16 + 4 * g;
#pragma unroll
    for (int i = 0; i < 4; ++i) mk[mi][i] = maskf[mbase + i];
  }
  float bval[4];
#pragma unroll
  for (int ni = 0; ni < 4; ++ni) bval[ni] = bias[nbase + wc * 64 + ni * 16 + c] * bscale;

  if (by < 8) {
#pragma unroll
    for (int ni = 0; ni < 4; ++ni) {
      int nloc = wc * 64 + ni * 16 + c;
#pragma unroll
      for (int mi = 0; mi < 4; ++mi) {
#pragma unroll
        for (int i = 0; i < 4; ++i) {
          int mloc = wr * 64 + mi * 16 + 4 * g + i;
          float v = (acc[mi][ni][i] + bval[ni]) * mk[mi][i];
          Lbuf[mloc * 128 + (nloc ^ ((mloc & 7) << 3))] = cvt1(v);
        }
      }
    }
    __syncthreads();
    short* outp = (by < 4) ? Qp : Kp;
    const int rrow = t >> 4, rcol = (t & 15) * 8;
#pragma unroll
    for (int p = 0; p < 8; ++p) {
      int m = p * 16 + rrow;
      bf16x8 vv = *(const bf16x8*)(Lbuf + m * 128 + (rcol ^ ((m & 7) << 3)));
      *(bf16x8*)(outp + (size_t)(m0 + m) * 512 + nbase + rcol) = vv;
    }
  } else {
#pragma unroll
    for (int ni = 0; ni < 4; ++ni) {
      int nloc = wc * 64 + ni * 16 + c;
#pragma unroll
      for (int mi = 0; mi < 4; ++mi) {
        int mloc4 = wr * 64 + mi * 16 + 4 * g;
        unsigned int lo = cvtpk((acc[mi][ni][0] + bval[ni]) * mk[mi][0],
                                (acc[mi][ni][1] + bval[ni]) * mk[mi][1]);
        unsigned int hi = cvtpk((acc[mi][ni][2] + bval[ni]) * mk[mi][2],
                                (acc[mi][ni][3] + bval[ni]) * mk[mi][3]);
        int ma = (mloc4 & 15) + (((mloc4 >> 4) ^ (nloc & 7)) << 4);
        uint2 uv; uv.x = lo; uv.y = hi;
        *(uint2*)(Lbuf + nloc * 128 + ma) = uv;
      }
    }
    __syncthreads();
    const int rrow = t >> 4, rcol = (t & 15) * 8;
#pragma unroll
    for (int p = 0; p < 8; ++p) {
      int n = p * 16 + rrow;
      int ma = (rcol & 8) + (((rcol >> 4) ^ (n & 7)) << 4);
      bf16x8 vv = *(const bf16x8*)(Lbuf + n * 128 + ma);
      int d = nbase + n;
      int hh = d >> 6, dd = d & 63;
      int mg = m0 + rcol;
      int bi = mg >> 10, seq0 = mg & 1023;
      *(bf16x8*)(Vt + ((size_t)((bi * 8 + hh) * 64 + dd)) * 1024 + seq0) = vv;
    }
  }
}

// ---------------- flash attention v7 (best measured): dbuf K/V + counted vmcnt.
// 2 waves x 32 q, KVBLK=64 in two kv-32 halves, 32x32 MFMA, in-register P,
// masked denominator, packed [r2][128] layouts (16-slot XOR -> 2-way free).
__global__ __launch_bounds__(128, 3) void attn7_kernel(
    const short* __restrict__ Qp, const short* __restrict__ Kp,
    const short* __restrict__ Vt, const float* __restrict__ mask,
    const short* __restrict__ mbf, short* __restrict__ Obb) {
  __shared__ short Kl[2][32 * 128];  // 16 KB dbuf; [0] reused as epilogue Tw
  __shared__ short Vl[2][32 * 128];  // 16 KB dbuf
  __shared__ short Ml[1024];         //  2 KB bf16 mask row
  const int t = threadIdx.x, lane = t & 63, w = t >> 6;  // w in {0,1}
  const int q32 = lane & 31, hi = lane >> 5;
  const int hw = blockIdx.x;
  const int L = (hw & 7) * 128 + (hw >> 3);  // XCD swizzle: 8 heads/XCD
  const int qt = L & 15, head = L >> 4;
  const int b = head & 7, h = head >> 3;
  const int n0 = qt * 64 + w * 32;

  const short* Kg = Kp + (size_t)(b * 1024) * 512 + h * 64;
  const short* Vg = Vt + (size_t)((b * 8 + h) * 64) * 1024;

  bf16x8 qf[4];
  {
    const short* qptr = Qp + ((size_t)(b * 1024 + n0 + q32) * 512 + h * 64 + 8 * hi);
#pragma unroll
    for (int kk = 0; kk < 4; ++kk) qf[kk] = *(const bf16x8*)(qptr + 16 * kk);
  }
  asm volatile("s_waitcnt vmcnt(0)" ::: "memory");  // qf resolved before staging begins
  __builtin_amdgcn_sched_barrier(0);

  auto STAGE = [&](int kvt, int buf) {
    const int kr = kvt * 64;
    short* Kd = &Kl[buf][0];
    short* Vd = &Vl[buf][0];
#pragma unroll
    for (int it = 0; it < 4; ++it) {
      int rb = it * 8 + w * 4;
      int r2 = rb + (lane >> 4);
      int sx = (lane & 15) ^ (r2 & 15);
      GLOAD_LDS16(Kg + (size_t)(kr + 2 * r2 + (sx >> 3)) * 512 + (sx & 7) * 8, Kd + rb * 128);
    }
#pragma unroll
    for (int it = 0; it < 4; ++it) {
      int rb = it * 8 + w * 4;
      int rv = rb + (lane >> 4);
      int sx = (lane & 15) ^ (rv & 15);
      GLOAD_LDS16(Vg + (size_t)(2 * rv + (sx >> 3)) * 1024 + kr + (sx & 7) * 8, Vd + rb * 128);
    }
  };

  // prologue: mask row (1 vm/wave) + tiles 0,1 (8 vm/wave each)
  GLOAD_LDS16(mbf + b * 1024 + w * 512 + lane * 8, Ml + w * 512);
  STAGE(0, 0);
  STAGE(1, 1);

  f32x16 o0, o1, suma;
#pragma unroll
  for (int e = 0; e < 16; ++e) { o0[e] = 0.f; o1[e] = 0.f; suma[e] = 0.f; }

#pragma unroll 1
  for (int kvt = 0; kvt < 16; ++kvt) {
    const int cur = kvt & 1;
    // counted wait: keep next tile's 8 loads in flight; only drain at the end
    if (kvt < 15) { asm volatile("s_waitcnt vmcnt(8)" ::: "memory"); }
    else          { asm volatile("s_waitcnt vmcnt(0)" ::: "memory"); }
    __builtin_amdgcn_sched_barrier(0);
    __builtin_amdgcn_s_barrier();  // buf[cur] visible to both waves
    __builtin_amdgcn_sched_barrier(0);

#pragma unroll
    for (int half = 0; half < 2; ++half) {
      // ---- just-in-time fragment reads for this kv-32 half
      bf16x8 ka[4], va[2][2], mo[2];
      {
        const int kvr = 32 * half + q32;
        const int r2 = kvr >> 1;
#pragma unroll
        for (int kk = 0; kk < 4; ++kk) {
          int sx = ((((kvr & 1) << 3) | (2 * kk + hi)) ^ (r2 & 15));
          ka[kk] = *(const bf16x8*)(&Kl[cur][0] + r2 * 128 + sx * 8);
        }
      }
#pragma unroll
      for (int ds = 0; ds < 2; ++ds) {
        const int d = 32 * ds + q32;
        const int rv = d >> 1;
#pragma unroll
        for (int ch = 0; ch < 2; ++ch) {
          int sx = ((((d & 1) << 3) | (4 * half + 2 * ch + hi)) ^ (rv & 15));
          va[ds][ch] = *(const bf16x8*)(&Vl[cur][0] + rv * 128 + sx * 8);
        }
      }
#pragma unroll
      for (int ch = 0; ch < 2; ++ch)  // broadcast
        mo[ch] = *(const bf16x8*)(Ml + kvt * 64 + 32 * half + 16 * ch + 8 * hi);

      __builtin_amdgcn_sched_barrier(0);
      asm volatile("s_waitcnt lgkmcnt(0)" ::: "memory");
      __builtin_amdgcn_sched_barrier(0);
      if (half == 1) {
        __builtin_amdgcn_s_barrier();  // both waves done reading buf[cur]
        __builtin_amdgcn_sched_barrier(0);
        if (kvt < 14) STAGE(kvt + 2, cur);  // async refill; lands a full tile later
        __builtin_amdgcn_sched_barrier(0);
      }

      // ---- QK^T for this half
      f32x16 s0;
#pragma unroll
      for (int e = 0; e < 16; ++e) s0[e] = 0.f;
      __builtin_amdgcn_s_setprio(1);
#pragma unroll
      for (int kk = 0; kk < 4; ++kk) s0 = MFMA32(ka[kk], qf[kk], s0);
      __builtin_amdgcn_s_setprio(0);

      // ---- p = exp2(s) (scale pre-folded into Kp)
      f32x16 p0;
#pragma unroll
      for (int e = 0; e < 16; ++e) p0[e] = vexp2(s0[e]);

      // ---- pack P^T fragments via cvt_pk + shfl_xor(32)
      bf16x8 pf[2];
#pragma unroll
      for (int ch = 0; ch < 2; ++ch) {
        unsigned int w01a = cvtpk(p0[8 * ch + 0], p0[8 * ch + 1]);
        unsigned int w01b = cvtpk(p0[8 * ch + 2], p0[8 * ch + 3]);
        unsigned int w23a = cvtpk(p0[8 * ch + 4], p0[8 * ch + 5]);
        unsigned int w23b = cvtpk(p0[8 * ch + 6], p0[8 * ch + 7]);
        unsigned int x0 = hi ? w01a : w23a;
        unsigned int x1 = hi ? w01b : w23b;
        unsigned int g0 = (unsigned int)__shfl_xor((int)x0, 32);
        unsigned int g1 = (unsigned int)__shfl_xor((int)x1, 32);
        union { unsigned int u[4]; bf16x8 v; } pu;
        pu.u[0] = hi ? g0 : w01a;
        pu.u[1] = hi ? g1 : w01b;
        pu.u[2] = hi ? w23a : g0;
        pu.u[3] = hi ? w23b : g1;
        pf[ch] = pu.v;
      }

      // ---- PV + masked denominator
      __builtin_amdgcn_s_setprio(1);
#pragma unroll
      for (int ch = 0; ch < 2; ++ch) {
        o0 = MFMA32(va[0][ch], pf[ch], o0);
        o1 = MFMA32(va[1][ch], pf[ch], o1);
        suma = MFMA32(mo[ch], pf[ch], suma);
      }
      __builtin_amdgcn_s_setprio(0);
    }
  }

  // ---- epilogue: normalize, per-wave LDS transpose (Kl[0] reuse), residual + row-mask
  short* Tw = &Kl[0][0] + w * 2304;  // 32x68 padded, per-wave disjoint
  const float inv = __builtin_amdgcn_rcpf(suma[0] + 1e-16f);
#pragma unroll
  for (int rr = 0; rr < 4; ++rr) {
    uint2 uv0, uv1;
    uv0.x = cvtpk(o0[4 * rr + 0] * inv, o0[4 * rr + 1] * inv);
    uv0.y = cvtpk(o0[4 * rr + 2] * inv, o0[4 * rr + 3] * inv);
    *(uint2*)(Tw + q32 * 68 + 8 * rr + 4 * hi) = uv0;
    uv1.x = cvtpk(o1[4 * rr + 0] * inv, o1[4 * rr + 1] * inv);
    uv1.y = cvtpk(o1[4 * rr + 2] * inv, o1[4 * rr + 3] * inv);
    *(uint2*)(Tw + q32 * 68 + 32 + 8 * rr + 4 * hi) = uv1;
  }
  asm volatile("s_waitcnt lgkmcnt(0)" ::: "memory");
  __builtin_amdgcn_sched_barrier(0);

  const int erow = lane >> 1, ecs = (lane & 1) * 8;
  const float mk1 = mask[b * 1024 + n0 + erow];
#pragma unroll
  for (int it = 0; it < 4; ++it) {
    int col = ecs + it * 16;
    bf16x8 av = *(const bf16x8*)(Tw + erow * 68 + col);
    const short* qptr = Qp + (size_t)(b * 1024 + n0 + erow) * 512 + h * 64 + col;
    bf16x8 qv = *(const bf16x8*)qptr;
    uint4 rr;
    rr.x = cvtpk(b2f((unsigned short)qv[0]) + mk1 * b2f((unsigned short)av[0]),
                 b2f((unsigned short)qv[1]) + mk1 * b2f((unsigned short)av[1]));
    rr.y = cvtpk(b2f((unsigned short)qv[2]) + mk1 * b2f((unsigned short)av[2]),
                 b2f((unsigned short)qv[3]) + mk1 * b2f((unsigned short)av[3]));
    rr.z = cvtpk(b2f((unsigned short)qv[4]) + mk1 * b2f((unsigned short)av[4]),
                 b2f((unsigned short)qv[5]) + mk1 * b2f((unsigned short)av[5]));
    rr.w = cvtpk(b2f((unsigned short)qv[6]) + mk1 * b2f((unsigned short)av[6]),
                 b2f((unsigned short)qv[7]) + mk1 * b2f((unsigned short)av[7]));
    *(uint4*)(Obb + (size_t)(b * 1024 + n0 + erow) * 512 + h * 64 + col) = rr;
  }
}

// ---------------- final: out = Obb + relu((Obb@Wo + bo) * mask)
__global__ __launch_bounds__(256) void final2_kernel(
    const short* __restrict__ Obb,
    const short* __restrict__ Wto, const float* __restrict__ bo,
    const float* __restrict__ maskf, float* __restrict__ out) {
  __shared__ short Lbuf[16384];
  const int m0 = blockIdx.x * 128, n0 = blockIdx.y * 128;
  const int t = threadIdx.x;
  const f32x4 zz = {0.f, 0.f, 0.f, 0.f};
  f32x4 acc[4][4];
#pragma unroll
  for (int mi = 0; mi < 4; ++mi)
#pragma unroll
    for (int ni = 0; ni < 4; ++ni) acc[mi][ni] = zz;
  gemm_bf16_core(Obb, Wto + n0 * 512, Lbuf, m0, t, acc);

  const int lane = t & 63, w = t >> 6;
  const int c = lane & 15, g = lane >> 4;
  const int wr = w >> 1, wc = w & 1;
  float mk[4][4];
#pragma unroll
  for (int mi = 0; mi < 4; ++mi) {
    int mbase = m0 + wr * 64 + mi * 16 + 4 * g;
#pragma unroll
    for (int i = 0; i < 4; ++i) mk[mi][i] = maskf[mbase + i];
  }
#pragma unroll
  for (int ni = 0; ni < 4; ++ni) {
    int n = n0 + wc * 64 + ni * 16 + c;
    float bval = bo[n];
#pragma unroll
    for (int mi = 0; mi < 4; ++mi) {
      int mbase = m0 + wr * 64 + mi * 16 + 4 * g;
#pragma unroll
      for (int i = 0; i < 4; ++i) {
        float v = (acc[mi][ni][i] + bval) * mk[mi][i];
        v = fmaxf(v, 0.f);
        size_t off = (size_t)(mbase + i) * 512 + n;
        out[off] = b2f((unsigned short)Obb[off]) + v;
      }
    }
  }
}

extern "C" void kernel_launch(void* const* d_in, const int* in_sizes, int n_in,
                              void* d_out, int out_size, void* d_ws, size_t ws_size,
                              hipStream_t stream) {
  (void)in_sizes; (void)n_in; (void)out_size; (void)ws_size;
  const float* Q    = (const float*)d_in[0];
  const float* K    = (const float*)d_in[1];
  const float* mask = (const float*)d_in[2];
  const float* Wq   = (const float*)d_in[3];
  const float* bq   = (const float*)d_in[4];
  const float* Wk   = (const float*)d_in[5];
  const float* bk   = (const float*)d_in[6];
  const float* Wv   = (const float*)d_in[7];
  const float* bv   = (const float*)d_in[8];
  const float* Wo   = (const float*)d_in[9];
  const float* bo   = (const float*)d_in[10];

  char* ws = (char*)d_ws;
  const size_t MB = 1048576;
  short* Wt4 = (short*)ws;                 // 0-2 MB (Wk pre-scaled by SCALE2)
  short* Qb  = (short*)(ws + 2 * MB);      // 2-10 MB (dead after proj2)
  short* Kb  = (short*)(ws + 10 * MB);     // 10-18 MB (dead after proj2)
  short* Qp  = (short*)(ws + 18 * MB);     // 18-26 MB
  short* Kp  = (short*)(ws + 26 * MB);     // 26-34 MB (pre-scaled)
  short* Vt  = (short*)(ws + 34 * MB);     // 34-42 MB: [B][H][64][1024]
  short* Obb = (short*)(ws + 42 * MB);     // 42-50 MB
  short* mbf = (short*)(ws + 50 * MB);     // 16 KB bf16 mask
  float* out = (float*)d_out;

  prep_kernel<<<dim3(4352), 256, 0, stream>>>(Wq, Wk, Wv, Wo, Q, K, mask, Wt4, Qb, Kb, mbf);
  proj2_kernel<<<dim3(64, 12), 256, 0, stream>>>(Qb, Kb, Wt4, bq, bk, bv, mask, Qp, Kp, Vt);
  attn7_kernel<<<dim3(1024), 128, 0, stream>>>(Qp, Kp, Vt, mask, mbf, Obb);
  final2_kernel<<<dim3(64, 4), 256, 0, stream>>>(Obb, Wt4 + 3 * 262144, bo, mask, out);
}